// Round 5
// baseline (256.029 us; speedup 1.0000x reference)
//
#include <hip/hip_runtime.h>

typedef _Float16 f16;
typedef _Float16 f16x8 __attribute__((ext_vector_type(8)));
typedef _Float16 f16x4 __attribute__((ext_vector_type(4)));
typedef float f32x4 __attribute__((ext_vector_type(4)));

#define MFMA16(a, b, c) __builtin_amdgcn_mfma_f32_16x16x32_f16((a), (b), (c), 0, 0, 0)

constexpr int Bs = 2, Ls = 2048, DIM = 1024, NH = 16, HD = 64;
constexpr int BL = Bs * Ls;  // 4096
constexpr float EPSV = 1e-6f;
constexpr float SCALE = 0.125f;    // 1/sqrt(64)
constexpr float SCL2 = 0.125f * 1.44269504f;  // SCALE * log2(e), for exp2

// ---------------- fp32 -> fp16 convert, all three tensors in one launch ----------------
__global__ void cvt_all_kernel(const float* __restrict__ x, const float* __restrict__ wq,
                               const float* __restrict__ wp, f16* __restrict__ xf,
                               f16* __restrict__ wqf, f16* __restrict__ wpf) {
  constexpr int NX4 = BL * DIM / 4;           // 1048576
  constexpr int NW4 = 3 * DIM * DIM / 4;      // 786432
  int i = blockIdx.x * blockDim.x + threadIdx.x;
  const float4* src;
  f16x4* dst;
  int j;
  if (i < NX4) {
    src = (const float4*)x; dst = (f16x4*)xf; j = i;
  } else if (i < NX4 + NW4) {
    src = (const float4*)wq; dst = (f16x4*)wqf; j = i - NX4;
  } else {
    src = (const float4*)wp; dst = (f16x4*)wpf; j = i - NX4 - NW4;
  }
  float4 a = src[j];
  f16x4 o = {(f16)a.x, (f16)a.y, (f16)a.z, (f16)a.w};
  dst[j] = o;
}

// ============ QKV GEMM: 128x128 tile, BK=64, REGISTER-RELAY double-buffer ============
// 256 thr = 4 waves in 2x2; each wave owns a 64x64 quadrant (4x4 16x16 tiles).
// Pipeline per iter: issue global->VGPR loads of tile k+1 (no wait), compute tile k from
// LDS[cur], then ds_write regs->LDS[nxt] (compiler's vmcnt wait lands HERE, after compute
// has hidden the load latency), barrier (lgkm only - fast). This avoids the
// global_load_lds pitfall where __syncthreads' vmcnt(0) drains the prefetch itself.
// XOR swizzle over all 8 16B-chunks of the 128B row -> frag b128 reads 2-way max (free).
__global__ __launch_bounds__(256) void qkv_gemm_kernel(
    const f16* __restrict__ A, const f16* __restrict__ W,
    const float* __restrict__ v0,
    const float* __restrict__ rcos, const float* __restrict__ rsin,
    const float* __restrict__ lamp,
    f16* __restrict__ qb, f16* __restrict__ kb, f16* __restrict__ vbT,
    float* __restrict__ vout) {
  constexpr int K = DIM;
  __shared__ alignas(16) f16 sA[2][128 * 64];
  __shared__ alignas(16) f16 sB[2][128 * 64];
  const int tid = threadIdx.x;
  const int w = tid >> 6, lane = tid & 63, ln = lane & 15, quad = lane >> 4;
  const int wm = w >> 1, wn = w & 1;
  const int m0 = blockIdx.y * 128, n0 = blockIdx.x * 128;

  const f16* gA[4];
  const f16* gB[4];
#pragma unroll
  for (int s = 0; s < 4; ++s) {
    int lc = tid + s * 256;              // LDS chunk 0..1023
    int r = lc >> 3;                     // row 0..127
    int c = ((lc & 7) ^ (r & 7)) * 8;    // permuted global chunk -> elems
    gA[s] = A + (size_t)(m0 + r) * K + c;
    gB[s] = W + (size_t)(n0 + r) * K + c;
  }

  f16x8 ra[4], rb[4];
  auto load = [&](int k0) {
#pragma unroll
    for (int s = 0; s < 4; ++s) {
      ra[s] = *(const f16x8*)(gA[s] + k0);
      rb[s] = *(const f16x8*)(gB[s] + k0);
    }
  };
  auto store = [&](int buf) {
#pragma unroll
    for (int s = 0; s < 4; ++s) {
      int lc = tid + s * 256;
      *(f16x8*)&sA[buf][lc * 8] = ra[s];
      *(f16x8*)&sB[buf][lc * 8] = rb[s];
    }
  };

  f32x4 acc[4][4] = {};
  load(0);
  store(0);
  __syncthreads();

  for (int it = 0; it < K / 64; ++it) {
    const int cur = it & 1;
    if (it + 1 < K / 64) load((it + 1) * 64);  // in flight across compute
#pragma unroll
    for (int kk = 0; kk < 2; ++kk) {
      f16x8 a[4];
#pragma unroll
      for (int mi = 0; mi < 4; ++mi) {
        int r = wm * 64 + mi * 16 + ln;
        a[mi] = *(const f16x8*)&sA[cur][r * 64 + (((kk * 4 + quad) ^ (r & 7)) * 8)];
      }
#pragma unroll
      for (int ni = 0; ni < 4; ++ni) {
        int r = wn * 64 + ni * 16 + ln;
        f16x8 b = *(const f16x8*)&sB[cur][r * 64 + (((kk * 4 + quad) ^ (r & 7)) * 8)];
#pragma unroll
        for (int mi = 0; mi < 4; ++mi) acc[mi][ni] = MFMA16(a[mi], b, acc[mi][ni]);
      }
    }
    if (it + 1 < K / 64) store(cur ^ 1);  // vmcnt wait here, after compute
    __syncthreads();                       // lgkm drain only
  }

  // Epilogue. Wave covers one head (64 cols). C/D: col=ln (in ni tile), row=quad*4+rg (in mi tile).
  const int nb = n0 + wn * 64;
  const int nsec = nb >> 10;        // 0=q, 1=k, 2=v
  const int h = (nb & 1023) >> 6;   // head

  if (nsec == 2) {
    const float lam = lamp[0];
#pragma unroll
    for (int mi = 0; mi < 4; ++mi) {
#pragma unroll
      for (int rg = 0; rg < 4; ++rg) {
        int row = m0 + wm * 64 + mi * 16 + quad * 4 + rg;
        int b = row >> 11, l = row & 2047;
        size_t base = ((size_t)(b * NH + h) * Ls + l) * HD;
        int lt = l & 63;
        int pos = ((lt & 15) << 2) | (lt >> 4);  // key-interleave for packed P writes in flash
        size_t tb = ((size_t)(b * NH + h) * HD) * Ls + (l & ~63) + pos;
#pragma unroll
        for (int ni = 0; ni < 4; ++ni) {
          int d = ni * 16 + ln;
          float vnew = lam * acc[mi][ni][rg] + (1.0f - lam) * v0[base + d];
          vout[base + d] = vnew;                     // fp32 output #1 (b,h,l,d)
          vbT[tb + (size_t)d * Ls] = (f16)vnew;      // (b,h,d, tile*64+pos) for flash PV
        }
      }
    }
  } else {
    f16* dst = nsec ? kb : qb;
    const float ratio = sqrtf(logf(2048.0f) / logf(1040.0f));
#pragma unroll
    for (int mi = 0; mi < 4; ++mi) {
#pragma unroll
      for (int rg = 0; rg < 4; ++rg) {
        int row = m0 + wm * 64 + mi * 16 + quad * 4 + rg;
        int b = row >> 11, l = row & 2047;
        float vals[4];
#pragma unroll
        for (int ni = 0; ni < 4; ++ni) vals[ni] = acc[mi][ni][rg];
        // RoPE: pair (d, d+32) == (vals[t], vals[t+2]), j = t*16+ln
#pragma unroll
        for (int t = 0; t < 2; ++t) {
          int j = t * 16 + ln;
          float c = rcos[l * 32 + j], s = rsin[l * 32 + j];
          float x1 = vals[t], x2 = vals[t + 2];
          vals[t] = x1 * c + x2 * s;
          vals[t + 2] = -x1 * s + x2 * c;
        }
        if (nsec) {
#pragma unroll
          for (int ni = 0; ni < 4; ++ni) vals[ni] *= ratio;
        }
        float ms = vals[0] * vals[0] + vals[1] * vals[1] + vals[2] * vals[2] + vals[3] * vals[3];
        ms += __shfl_xor(ms, 1);
        ms += __shfl_xor(ms, 2);
        ms += __shfl_xor(ms, 4);
        ms += __shfl_xor(ms, 8);
        float rn = rsqrtf(ms * (1.0f / 64.0f) + EPSV);
        size_t base = ((size_t)(b * NH + h) * Ls + l) * HD;
#pragma unroll
        for (int ni = 0; ni < 4; ++ni) dst[base + ni * 16 + ln] = (f16)(vals[ni] * rn);
      }
    }
  }
}

// ============ Flash attention: 128-row Q tile, reg-prefetch dbuf K/V, packed P ============
// One block per (b, h, 128-row q tile); wave w owns 16-row strips at st*64 + w*16, st=0,1.
// sP wave-private -> no barrier around the P LDS roundtrip. One barrier per k-tile.
__global__ __launch_bounds__(256) void flash_kernel(
    const f16* __restrict__ qg, const f16* __restrict__ kg, const f16* __restrict__ vtg,
    f16* __restrict__ ao) {
  __shared__ alignas(16) f16 sQ[128 * 72];
  __shared__ alignas(16) f16 sK[2][64 * 72];
  __shared__ alignas(16) f16 sVT[2][64 * 72];  // [d][pos] (pre-interleaved keys)
  __shared__ alignas(16) f16 sP[128 * 72];     // [qrow][pos]
  const int tid = threadIdx.x;
  const int w = tid >> 6, lane = tid & 63, ln = lane & 15, quad = lane >> 4;
  const int bx = blockIdx.x;
  const int qt = bx & 15, h = (bx >> 4) & 15, b = bx >> 8;
  const f16* Qh = qg + (size_t)(b * NH + h) * Ls * HD;
  const f16* Kh = kg + (size_t)(b * NH + h) * Ls * HD;
  const f16* VTh = vtg + (size_t)(b * NH + h) * HD * Ls;
  const int q0 = qt * 128;

  // stage Q (128x64) + K/VT tile 0 (64x64 each)
#pragma unroll
  for (int s = 0; s < 4; ++s) {
    int e = tid + s * 256, row = e >> 3, c8 = (e & 7) * 8;
    *(f16x8*)&sQ[row * 72 + c8] = *(const f16x8*)&Qh[(size_t)(q0 + row) * HD + c8];
  }
#pragma unroll
  for (int s = 0; s < 2; ++s) {
    int e = tid + s * 256, row = e >> 3, c8 = (e & 7) * 8;
    *(f16x8*)&sK[0][row * 72 + c8] = *(const f16x8*)&Kh[(size_t)row * HD + c8];
    *(f16x8*)&sVT[0][row * 72 + c8] = *(const f16x8*)&VTh[(size_t)row * Ls + c8];
  }
  __syncthreads();

  f16x8 aq[2][2];
#pragma unroll
  for (int st = 0; st < 2; ++st)
#pragma unroll
    for (int kk = 0; kk < 2; ++kk)
      aq[st][kk] = *(const f16x8*)&sQ[(st * 64 + w * 16 + ln) * 72 + kk * 32 + quad * 8];

  f32x4 O[2][4] = {};
  float rsum[2][4] = {};

  for (int kt = 0; kt < 32; ++kt) {
    const int cur = kt & 1;
    f16x8 kr[2], vr[2];
    if (kt < 31) {  // prefetch next k-tile into registers; overlaps this tile's compute
      const int k0n = (kt + 1) * 64;
#pragma unroll
      for (int s = 0; s < 2; ++s) {
        int e = tid + s * 256, row = e >> 3, c8 = (e & 7) * 8;
        kr[s] = *(const f16x8*)&Kh[(size_t)(k0n + row) * HD + c8];
        vr[s] = *(const f16x8*)&VTh[(size_t)row * Ls + k0n + c8];
      }
    }

    // S = Q K^T
    f32x4 S[2][4];
#pragma unroll
    for (int nt = 0; nt < 4; ++nt) {
      f16x8 bk0 = *(const f16x8*)&sK[cur][(nt * 16 + ln) * 72 + quad * 8];
      f16x8 bk1 = *(const f16x8*)&sK[cur][(nt * 16 + ln) * 72 + 32 + quad * 8];
#pragma unroll
      for (int st = 0; st < 2; ++st) {
        f32x4 z = {};
        z = MFMA16(aq[st][0], bk0, z);
        z = MFMA16(aq[st][1], bk1, z);
        S[st][nt] = z;
      }
    }

    // p = exp2(score * scale * log2e) (no max-shift: |score| <= 8.4 post-RMSnorm).
    // P[qrow][pos], pos = (key%16)*4 + key/16: thread's 4 nt-values are contiguous (b64 write).
#pragma unroll
    for (int st = 0; st < 2; ++st) {
#pragma unroll
      for (int rg = 0; rg < 4; ++rg) {
        float p0 = exp2f(S[st][0][rg] * SCL2);
        float p1 = exp2f(S[st][1][rg] * SCL2);
        float p2 = exp2f(S[st][2][rg] * SCL2);
        float p3 = exp2f(S[st][3][rg] * SCL2);
        rsum[st][rg] += p0 + p1 + p2 + p3;
        f16x4 pk = {(f16)p0, (f16)p1, (f16)p2, (f16)p3};
        *(f16x4*)&sP[(st * 64 + w * 16 + quad * 4 + rg) * 72 + ln * 4] = pk;
      }
    }

    // O += P V  (A = P rows [q][pos], B = VT [d][pos]; k permuted consistently)
    f16x8 ap[2][2];
#pragma unroll
    for (int st = 0; st < 2; ++st) {
      ap[st][0] = *(const f16x8*)&sP[(st * 64 + w * 16 + ln) * 72 + quad * 8];
      ap[st][1] = *(const f16x8*)&sP[(st * 64 + w * 16 + ln) * 72 + 32 + quad * 8];
    }
#pragma unroll
    for (int nt = 0; nt < 4; ++nt) {
      f16x8 bv0 = *(const f16x8*)&sVT[cur][(nt * 16 + ln) * 72 + quad * 8];
      f16x8 bv1 = *(const f16x8*)&sVT[cur][(nt * 16 + ln) * 72 + 32 + quad * 8];
#pragma unroll
      for (int st = 0; st < 2; ++st) {
        O[st][nt] = MFMA16(ap[st][0], bv0, O[st][nt]);
        O[st][nt] = MFMA16(ap[st][1], bv1, O[st][nt]);
      }
    }

    if (kt < 31) {
      const int nxt = cur ^ 1;
#pragma unroll
      for (int s = 0; s < 2; ++s) {
        int e = tid + s * 256, row = e >> 3, c8 = (e & 7) * 8;
        *(f16x8*)&sK[nxt][row * 72 + c8] = kr[s];
        *(f16x8*)&sVT[nxt][row * 72 + c8] = vr[s];
      }
    }
    __syncthreads();
  }

  // epilogue: reduce row sums once, normalize, store fp16 attn-out in (b,l,dim)
#pragma unroll
  for (int st = 0; st < 2; ++st) {
#pragma unroll
    for (int rg = 0; rg < 4; ++rg) {
      float rs = rsum[st][rg];
      rs += __shfl_xor(rs, 1);
      rs += __shfl_xor(rs, 2);
      rs += __shfl_xor(rs, 4);
      rs += __shfl_xor(rs, 8);
      float inv = 1.0f / rs;
      int l = q0 + st * 64 + w * 16 + quad * 4 + rg;
      size_t orow = ((size_t)b * Ls + l) * DIM + h * HD;
#pragma unroll
      for (int nt = 0; nt < 4; ++nt)
        ao[orow + nt * 16 + ln] = (f16)(O[st][nt][rg] * inv);
    }
  }
}

// ============ proj GEMM: fp16 BK=64 core, register-relay double-buffer, fp32 out ============
__global__ __launch_bounds__(256) void proj_gemm_kernel(
    const f16* __restrict__ A, const f16* __restrict__ W, float* __restrict__ out) {
  constexpr int K = DIM;
  __shared__ alignas(16) f16 sA[2][128 * 64];
  __shared__ alignas(16) f16 sB[2][128 * 64];
  const int tid = threadIdx.x;
  const int w = tid >> 6, lane = tid & 63, ln = lane & 15, quad = lane >> 4;
  const int wm = w >> 1, wn = w & 1;
  const int m0 = blockIdx.y * 128, n0 = blockIdx.x * 128;

  const f16* gA[4];
  const f16* gB[4];
#pragma unroll
  for (int s = 0; s < 4; ++s) {
    int lc = tid + s * 256;
    int r = lc >> 3;
    int c = ((lc & 7) ^ (r & 7)) * 8;
    gA[s] = A + (size_t)(m0 + r) * K + c;
    gB[s] = W + (size_t)(n0 + r) * K + c;
  }

  f16x8 ra[4], rb[4];
  auto load = [&](int k0) {
#pragma unroll
    for (int s = 0; s < 4; ++s) {
      ra[s] = *(const f16x8*)(gA[s] + k0);
      rb[s] = *(const f16x8*)(gB[s] + k0);
    }
  };
  auto store = [&](int buf) {
#pragma unroll
    for (int s = 0; s < 4; ++s) {
      int lc = tid + s * 256;
      *(f16x8*)&sA[buf][lc * 8] = ra[s];
      *(f16x8*)&sB[buf][lc * 8] = rb[s];
    }
  };

  f32x4 acc[4][4] = {};
  load(0);
  store(0);
  __syncthreads();

  for (int it = 0; it < K / 64; ++it) {
    const int cur = it & 1;
    if (it + 1 < K / 64) load((it + 1) * 64);
#pragma unroll
    for (int kk = 0; kk < 2; ++kk) {
      f16x8 a[4];
#pragma unroll
      for (int mi = 0; mi < 4; ++mi) {
        int r = wm * 64 + mi * 16 + ln;
        a[mi] = *(const f16x8*)&sA[cur][r * 64 + (((kk * 4 + quad) ^ (r & 7)) * 8)];
      }
#pragma unroll
      for (int ni = 0; ni < 4; ++ni) {
        int r = wn * 64 + ni * 16 + ln;
        f16x8 b = *(const f16x8*)&sB[cur][r * 64 + (((kk * 4 + quad) ^ (r & 7)) * 8)];
#pragma unroll
        for (int mi = 0; mi < 4; ++mi) acc[mi][ni] = MFMA16(a[mi], b, acc[mi][ni]);
      }
    }
    if (it + 1 < K / 64) store(cur ^ 1);
    __syncthreads();
  }

#pragma unroll
  for (int mi = 0; mi < 4; ++mi) {
#pragma unroll
    for (int rg = 0; rg < 4; ++rg) {
      int row = m0 + wm * 64 + mi * 16 + quad * 4 + rg;
      size_t o = (size_t)row * DIM + n0 + wn * 64;
#pragma unroll
      for (int ni = 0; ni < 4; ++ni) out[o + ni * 16 + ln] = acc[mi][ni][rg];
    }
  }
}

extern "C" void kernel_launch(void* const* d_in, const int* in_sizes, int n_in,
                              void* d_out, int out_size, void* d_ws, size_t ws_size,
                              hipStream_t stream) {
  (void)in_sizes; (void)n_in; (void)out_size; (void)ws_size;
  const float* x = (const float*)d_in[0];
  const float* v0 = (const float*)d_in[1];
  const float* rcos = (const float*)d_in[2];
  const float* rsin = (const float*)d_in[3];
  const float* wqkv = (const float*)d_in[4];
  const float* wproj = (const float*)d_in[5];
  const float* lamp = (const float*)d_in[6];
  float* out = (float*)d_out;
  float* vout = out + (size_t)BL * DIM;  // output #1: blended v, (B,H,L,HD)

  char* p = (char*)d_ws;
  auto take = [&](size_t n) { char* q = p; p += ((n + 255) / 256) * 256; return q; };
  f16* xf = (f16*)take((size_t)BL * DIM * 2);
  f16* wqf = (f16*)take((size_t)3 * DIM * DIM * 2);
  f16* wpf = (f16*)take((size_t)DIM * DIM * 2);
  f16* qb = (f16*)take((size_t)BL * DIM * 2);
  f16* kb = (f16*)take((size_t)BL * DIM * 2);
  f16* vbT = (f16*)take((size_t)BL * DIM * 2);  // (b,h,d, key-interleaved l)
  f16* ao = xf;  // x dead after qkv_gemm; reuse (stream-ordered)

  constexpr int NCVT4 = (BL * DIM + 3 * DIM * DIM + DIM * DIM) / 4;  // 2097152
  cvt_all_kernel<<<dim3(NCVT4 / 256), dim3(256), 0, stream>>>(x, wqkv, wproj, xf, wqf, wpf);

  qkv_gemm_kernel<<<dim3(3 * DIM / 128, BL / 128), dim3(256), 0, stream>>>(
      xf, wqf, v0, rcos, rsin, lamp, qb, kb, vbT, vout);

  flash_kernel<<<dim3(Bs * NH * (Ls / 128)), dim3(256), 0, stream>>>(qb, kb, vbT, ao);

  proj_gemm_kernel<<<dim3(DIM / 128, BL / 128), dim3(256), 0, stream>>>(ao, wpf, out);
}

// Round 6
// 241.895 us; speedup vs baseline: 1.0584x; 1.0584x over previous
//
#include <hip/hip_runtime.h>

typedef _Float16 f16;
typedef _Float16 f16x8 __attribute__((ext_vector_type(8)));
typedef _Float16 f16x4 __attribute__((ext_vector_type(4)));
typedef float f32x4 __attribute__((ext_vector_type(4)));

#define MFMA32(a, b, c) __builtin_amdgcn_mfma_f32_16x16x32_f16((a), (b), (c), 0, 0, 0)
#define MFMA16(a, b, c) __builtin_amdgcn_mfma_f32_16x16x16f16((a), (b), (c), 0, 0, 0)

constexpr int Bs = 2, Ls = 2048, DIM = 1024, NH = 16, HD = 64;
constexpr int BL = Bs * Ls;  // 4096
constexpr float EPSV = 1e-6f;
constexpr float SCL2 = 0.125f * 1.44269504f;  // (1/sqrt(64)) * log2(e), for exp2

// ---------------- fp32 -> fp16 convert, all three tensors in one launch ----------------
__global__ void cvt_all_kernel(const float* __restrict__ x, const float* __restrict__ wq,
                               const float* __restrict__ wp, f16* __restrict__ xf,
                               f16* __restrict__ wqf, f16* __restrict__ wpf) {
  constexpr int NX4 = BL * DIM / 4;           // 1048576
  constexpr int NW4 = 3 * DIM * DIM / 4;      // 786432
  int i = blockIdx.x * blockDim.x + threadIdx.x;
  const float4* src;
  f16x4* dst;
  int j;
  if (i < NX4) {
    src = (const float4*)x; dst = (f16x4*)xf; j = i;
  } else if (i < NX4 + NW4) {
    src = (const float4*)wq; dst = (f16x4*)wqf; j = i - NX4;
  } else {
    src = (const float4*)wp; dst = (f16x4*)wpf; j = i - NX4 - NW4;
  }
  float4 a = src[j];
  f16x4 o = {(f16)a.x, (f16)a.y, (f16)a.z, (f16)a.w};
  dst[j] = o;
}

// ============ QKV GEMM: 128x128 tile, BK=64, register-relay double-buffer ============
// (unchanged from R5 except vbT is now a PLAIN (b,h,d,l) transpose - no key interleave)
__global__ __launch_bounds__(256) void qkv_gemm_kernel(
    const f16* __restrict__ A, const f16* __restrict__ W,
    const float* __restrict__ v0,
    const float* __restrict__ rcos, const float* __restrict__ rsin,
    const float* __restrict__ lamp,
    f16* __restrict__ qb, f16* __restrict__ kb, f16* __restrict__ vbT,
    float* __restrict__ vout) {
  constexpr int K = DIM;
  __shared__ alignas(16) f16 sA[2][128 * 64];
  __shared__ alignas(16) f16 sB[2][128 * 64];
  const int tid = threadIdx.x;
  const int w = tid >> 6, lane = tid & 63, ln = lane & 15, quad = lane >> 4;
  const int wm = w >> 1, wn = w & 1;
  const int m0 = blockIdx.y * 128, n0 = blockIdx.x * 128;

  const f16* gA[4];
  const f16* gB[4];
#pragma unroll
  for (int s = 0; s < 4; ++s) {
    int lc = tid + s * 256;              // LDS chunk 0..1023
    int r = lc >> 3;                     // row 0..127
    int c = ((lc & 7) ^ (r & 7)) * 8;    // XOR-swizzled global chunk
    gA[s] = A + (size_t)(m0 + r) * K + c;
    gB[s] = W + (size_t)(n0 + r) * K + c;
  }

  f16x8 ra[4], rb[4];
  auto load = [&](int k0) {
#pragma unroll
    for (int s = 0; s < 4; ++s) {
      ra[s] = *(const f16x8*)(gA[s] + k0);
      rb[s] = *(const f16x8*)(gB[s] + k0);
    }
  };
  auto store = [&](int buf) {
#pragma unroll
    for (int s = 0; s < 4; ++s) {
      int lc = tid + s * 256;
      *(f16x8*)&sA[buf][lc * 8] = ra[s];
      *(f16x8*)&sB[buf][lc * 8] = rb[s];
    }
  };

  f32x4 acc[4][4] = {};
  load(0);
  store(0);
  __syncthreads();

  for (int it = 0; it < K / 64; ++it) {
    const int cur = it & 1;
    if (it + 1 < K / 64) load((it + 1) * 64);  // in flight across compute
#pragma unroll
    for (int kk = 0; kk < 2; ++kk) {
      f16x8 a[4];
#pragma unroll
      for (int mi = 0; mi < 4; ++mi) {
        int r = wm * 64 + mi * 16 + ln;
        a[mi] = *(const f16x8*)&sA[cur][r * 64 + (((kk * 4 + quad) ^ (r & 7)) * 8)];
      }
#pragma unroll
      for (int ni = 0; ni < 4; ++ni) {
        int r = wn * 64 + ni * 16 + ln;
        f16x8 b = *(const f16x8*)&sB[cur][r * 64 + (((kk * 4 + quad) ^ (r & 7)) * 8)];
#pragma unroll
        for (int mi = 0; mi < 4; ++mi) acc[mi][ni] = MFMA32(a[mi], b, acc[mi][ni]);
      }
    }
    if (it + 1 < K / 64) store(cur ^ 1);  // vmcnt wait lands here, after compute
    __syncthreads();                       // lgkm drain only
  }

  const int nb = n0 + wn * 64;
  const int nsec = nb >> 10;        // 0=q, 1=k, 2=v
  const int h = (nb & 1023) >> 6;   // head

  if (nsec == 2) {
    const float lam = lamp[0];
#pragma unroll
    for (int mi = 0; mi < 4; ++mi) {
#pragma unroll
      for (int rg = 0; rg < 4; ++rg) {
        int row = m0 + wm * 64 + mi * 16 + quad * 4 + rg;
        int b = row >> 11, l = row & 2047;
        size_t base = ((size_t)(b * NH + h) * Ls + l) * HD;
        size_t tb = ((size_t)(b * NH + h) * HD) * Ls + l;
#pragma unroll
        for (int ni = 0; ni < 4; ++ni) {
          int d = ni * 16 + ln;
          float vnew = lam * acc[mi][ni][rg] + (1.0f - lam) * v0[base + d];
          vout[base + d] = vnew;                 // fp32 output #1 (b,h,l,d)
          vbT[tb + (size_t)d * Ls] = (f16)vnew;  // plain transpose (b,h,d,l)
        }
      }
    }
  } else {
    f16* dst = nsec ? kb : qb;
    const float ratio = sqrtf(logf(2048.0f) / logf(1040.0f));
#pragma unroll
    for (int mi = 0; mi < 4; ++mi) {
#pragma unroll
      for (int rg = 0; rg < 4; ++rg) {
        int row = m0 + wm * 64 + mi * 16 + quad * 4 + rg;
        int b = row >> 11, l = row & 2047;
        float vals[4];
#pragma unroll
        for (int ni = 0; ni < 4; ++ni) vals[ni] = acc[mi][ni][rg];
#pragma unroll
        for (int t = 0; t < 2; ++t) {
          int j = t * 16 + ln;
          float c = rcos[l * 32 + j], s = rsin[l * 32 + j];
          float x1 = vals[t], x2 = vals[t + 2];
          vals[t] = x1 * c + x2 * s;
          vals[t + 2] = -x1 * s + x2 * c;
        }
        if (nsec) {
#pragma unroll
          for (int ni = 0; ni < 4; ++ni) vals[ni] *= ratio;
        }
        float ms = vals[0] * vals[0] + vals[1] * vals[1] + vals[2] * vals[2] + vals[3] * vals[3];
        ms += __shfl_xor(ms, 1);
        ms += __shfl_xor(ms, 2);
        ms += __shfl_xor(ms, 4);
        ms += __shfl_xor(ms, 8);
        float rn = rsqrtf(ms * (1.0f / 64.0f) + EPSV);
        size_t base = ((size_t)(b * NH + h) * Ls + l) * HD;
#pragma unroll
        for (int ni = 0; ni < 4; ++ni) dst[base + ni * 16 + ln] = (f16)(vals[ni] * rn);
      }
    }
  }
}

// ============ Flash attention, S^T operand-swap: no P LDS round-trip, no sQ ============
// S^T = K·Q^T via mfma 16x16x32 (A=K-frag, B=Q-frag). S^T's C-layout (key=quad*4+rg, q=ln)
// IS the A-operand layout of mfma_f32_16x16x16_f16 (m=ln, k=quad*4+j) -> exp in registers,
// feed PV directly. Q B-frags load once from global. LDS = K/VT dbuf only (32 KB).
// One block per (b,h,128-q tile); wave w owns q-cols [w*32, w*32+32) as 2 st-tiles of 16.
__global__ __launch_bounds__(256) void flash_kernel(
    const f16* __restrict__ qg, const f16* __restrict__ kg, const f16* __restrict__ vtg,
    f16* __restrict__ ao) {
  __shared__ alignas(16) f16 sK[2][64 * 64];
  __shared__ alignas(16) f16 sVT[2][64 * 64];  // [d][key]
  const int tid = threadIdx.x;
  const int w = tid >> 6, lane = tid & 63, ln = lane & 15, quad = lane >> 4;
  const int bx = blockIdx.x;
  const int qt = bx & 15, h = (bx >> 4) & 15, b = bx >> 8;
  const f16* Qh = qg + (size_t)(b * NH + h) * Ls * HD;
  const f16* Kh = kg + (size_t)(b * NH + h) * Ls * HD;
  const f16* VTh = vtg + (size_t)(b * NH + h) * HD * Ls;
  const int q0 = qt * 128;

  // Q as B-frags straight from global: B[k=hd][n=q], lane ln = q-col, hd = kk*32+quad*8+j
  f16x8 aq[2][2];
#pragma unroll
  for (int st = 0; st < 2; ++st)
#pragma unroll
    for (int kk = 0; kk < 2; ++kk)
      aq[st][kk] = *(const f16x8*)&Qh[(size_t)(q0 + w * 32 + st * 16 + ln) * HD + kk * 32 + quad * 8];

  // staging map: chunk ch = s*256+tid -> row r = ch>>3 (64 rows), global col (ch&7)*8,
  // physical col XOR-swizzled by (r&7) -> balanced banks for writes and frag reads.
  f16x8 kr[2], vr[2];
  auto loadKV = [&](int k0) {
#pragma unroll
    for (int s = 0; s < 2; ++s) {
      int ch = tid + s * 256, r = ch >> 3, cg = (ch & 7) * 8;
      kr[s] = *(const f16x8*)&Kh[(size_t)(k0 + r) * HD + cg];
      vr[s] = *(const f16x8*)&VTh[(size_t)r * Ls + k0 + cg];
    }
  };
  auto stageKV = [&](int buf) {
#pragma unroll
    for (int s = 0; s < 2; ++s) {
      int ch = tid + s * 256, r = ch >> 3;
      int po = r * 64 + (((ch & 7) ^ (r & 7)) * 8);
      *(f16x8*)&sK[buf][po] = kr[s];
      *(f16x8*)&sVT[buf][po] = vr[s];
    }
  };

  f32x4 O[2][4] = {};
  float rsum[2] = {0.f, 0.f};

  loadKV(0);
  stageKV(0);
  __syncthreads();

  for (int kt = 0; kt < 32; ++kt) {
    const int cur = kt & 1;
    if (kt < 31) loadKV((kt + 1) * 64);  // global->reg prefetch, in flight across compute

    // S^T tiles (key-tile nt x q-tile st) + in-register softmax -> PV A-frags
    f16x4 pf[2][4];
#pragma unroll
    for (int nt = 0; nt < 4; ++nt) {
      int r = nt * 16 + ln;  // key row
      f16x8 kf0 = *(const f16x8*)&sK[cur][r * 64 + ((quad ^ (r & 7)) * 8)];
      f16x8 kf1 = *(const f16x8*)&sK[cur][r * 64 + (((4 + quad) ^ (r & 7)) * 8)];
#pragma unroll
      for (int st = 0; st < 2; ++st) {
        f32x4 z = {};
        z = MFMA32(kf0, aq[st][0], z);
        z = MFMA32(kf1, aq[st][1], z);
        float p0 = exp2f(z[0] * SCL2);
        float p1 = exp2f(z[1] * SCL2);
        float p2 = exp2f(z[2] * SCL2);
        float p3 = exp2f(z[3] * SCL2);
        rsum[st] += (p0 + p1) + (p2 + p3);
        f16x4 pk = {(f16)p0, (f16)p1, (f16)p2, (f16)p3};
        pf[st][nt] = pk;
      }
    }

    // O += P·V via mfma 16x16x16: A = pf (q=ln, key=quad*4+j), B = V-frag from sVT
#pragma unroll
    for (int dt = 0; dt < 4; ++dt) {
      int row = dt * 16 + ln;  // d row of VT
#pragma unroll
      for (int nt = 0; nt < 4; ++nt) {
        int cv = nt * 2 + (quad >> 1);  // 16B chunk holding keys nt*16+quad*4..+3
        f16x4 vf = *(const f16x4*)&sVT[cur][row * 64 + ((cv ^ (row & 7)) * 8) + (quad & 1) * 4];
#pragma unroll
        for (int st = 0; st < 2; ++st) O[st][dt] = MFMA16(pf[st][nt], vf, O[st][dt]);
      }
    }

    if (kt < 31) stageKV(cur ^ 1);  // vmcnt wait lands here, after compute
    __syncthreads();
  }

  // epilogue: reduce row sums over quads, normalize, store fp16 attn-out (b,l,dim)
#pragma unroll
  for (int st = 0; st < 2; ++st) {
    float rs = rsum[st];
    rs += __shfl_xor(rs, 16);
    rs += __shfl_xor(rs, 32);  // every lane now holds rowsum(q-local = ln)
#pragma unroll
    for (int rg = 0; rg < 4; ++rg) {
      float inv = 1.0f / __shfl(rs, quad * 4 + rg);
      int q = q0 + w * 32 + st * 16 + quad * 4 + rg;
      size_t orow = ((size_t)b * Ls + q) * DIM + h * HD;
#pragma unroll
      for (int dt = 0; dt < 4; ++dt)
        ao[orow + dt * 16 + ln] = (f16)(O[st][dt][rg] * inv);
    }
  }
}

// ============ proj GEMM: 64x128 tile (512 blocks = 2/CU), register-relay dbuf ============
__global__ __launch_bounds__(256) void proj_gemm_kernel(
    const f16* __restrict__ A, const f16* __restrict__ W, float* __restrict__ out) {
  constexpr int K = DIM;
  __shared__ alignas(16) f16 sA[2][64 * 64];
  __shared__ alignas(16) f16 sB[2][128 * 64];
  const int tid = threadIdx.x;
  const int w = tid >> 6, lane = tid & 63, ln = lane & 15, quad = lane >> 4;
  const int wm = w >> 1, wn = w & 1;  // wave: 32 rows x 64 cols
  const int m0 = blockIdx.y * 64, n0 = blockIdx.x * 128;

  const f16* gA[2];
  const f16* gB[4];
#pragma unroll
  for (int s = 0; s < 2; ++s) {
    int lc = tid + s * 256;
    int r = lc >> 3;
    gA[s] = A + (size_t)(m0 + r) * K + (((lc & 7) ^ (r & 7)) * 8);
  }
#pragma unroll
  for (int s = 0; s < 4; ++s) {
    int lc = tid + s * 256;
    int r = lc >> 3;
    gB[s] = W + (size_t)(n0 + r) * K + (((lc & 7) ^ (r & 7)) * 8);
  }

  f16x8 ra[2], rb[4];
  auto load = [&](int k0) {
#pragma unroll
    for (int s = 0; s < 2; ++s) ra[s] = *(const f16x8*)(gA[s] + k0);
#pragma unroll
    for (int s = 0; s < 4; ++s) rb[s] = *(const f16x8*)(gB[s] + k0);
  };
  auto store = [&](int buf) {
#pragma unroll
    for (int s = 0; s < 2; ++s) *(f16x8*)&sA[buf][(tid + s * 256) * 8] = ra[s];
#pragma unroll
    for (int s = 0; s < 4; ++s) *(f16x8*)&sB[buf][(tid + s * 256) * 8] = rb[s];
  };

  f32x4 acc[2][4] = {};
  load(0);
  store(0);
  __syncthreads();

  for (int it = 0; it < K / 64; ++it) {
    const int cur = it & 1;
    if (it + 1 < K / 64) load((it + 1) * 64);
#pragma unroll
    for (int kk = 0; kk < 2; ++kk) {
      f16x8 a[2];
#pragma unroll
      for (int mi = 0; mi < 2; ++mi) {
        int r = wm * 32 + mi * 16 + ln;
        a[mi] = *(const f16x8*)&sA[cur][r * 64 + (((kk * 4 + quad) ^ (r & 7)) * 8)];
      }
#pragma unroll
      for (int ni = 0; ni < 4; ++ni) {
        int r = wn * 64 + ni * 16 + ln;
        f16x8 b = *(const f16x8*)&sB[cur][r * 64 + (((kk * 4 + quad) ^ (r & 7)) * 8)];
#pragma unroll
        for (int mi = 0; mi < 2; ++mi) acc[mi][ni] = MFMA32(a[mi], b, acc[mi][ni]);
      }
    }
    if (it + 1 < K / 64) store(cur ^ 1);
    __syncthreads();
  }

#pragma unroll
  for (int mi = 0; mi < 2; ++mi) {
#pragma unroll
    for (int rg = 0; rg < 4; ++rg) {
      int row = m0 + wm * 32 + mi * 16 + quad * 4 + rg;
      size_t o = (size_t)row * DIM + n0 + wn * 64;
#pragma unroll
      for (int ni = 0; ni < 4; ++ni) out[o + ni * 16 + ln] = acc[mi][ni][rg];
    }
  }
}

extern "C" void kernel_launch(void* const* d_in, const int* in_sizes, int n_in,
                              void* d_out, int out_size, void* d_ws, size_t ws_size,
                              hipStream_t stream) {
  (void)in_sizes; (void)n_in; (void)out_size; (void)ws_size;
  const float* x = (const float*)d_in[0];
  const float* v0 = (const float*)d_in[1];
  const float* rcos = (const float*)d_in[2];
  const float* rsin = (const float*)d_in[3];
  const float* wqkv = (const float*)d_in[4];
  const float* wproj = (const float*)d_in[5];
  const float* lamp = (const float*)d_in[6];
  float* out = (float*)d_out;
  float* vout = out + (size_t)BL * DIM;  // output #1: blended v, (B,H,L,HD)

  char* p = (char*)d_ws;
  auto take = [&](size_t n) { char* q = p; p += ((n + 255) / 256) * 256; return q; };
  f16* xf = (f16*)take((size_t)BL * DIM * 2);
  f16* wqf = (f16*)take((size_t)3 * DIM * DIM * 2);
  f16* wpf = (f16*)take((size_t)DIM * DIM * 2);
  f16* qb = (f16*)take((size_t)BL * DIM * 2);
  f16* kb = (f16*)take((size_t)BL * DIM * 2);
  f16* vbT = (f16*)take((size_t)BL * DIM * 2);  // (b,h,d,l) plain transpose
  f16* ao = xf;  // x dead after qkv_gemm; reuse (stream-ordered)

  constexpr int NCVT4 = (BL * DIM + 3 * DIM * DIM + DIM * DIM) / 4;  // 2097152
  cvt_all_kernel<<<dim3(NCVT4 / 256), dim3(256), 0, stream>>>(x, wqkv, wproj, xf, wqf, wpf);

  qkv_gemm_kernel<<<dim3(3 * DIM / 128, BL / 128), dim3(256), 0, stream>>>(
      xf, wqf, v0, rcos, rsin, lamp, qb, kb, vbT, vout);

  flash_kernel<<<dim3(Bs * NH * (Ls / 128)), dim3(256), 0, stream>>>(qb, kb, vbT, ao);

  proj_gemm_kernel<<<dim3(DIM / 128, BL / 64), dim3(256), 0, stream>>>(ao, wpf, out);
}

// Round 7
// 239.052 us; speedup vs baseline: 1.0710x; 1.0119x over previous
//
#include <hip/hip_runtime.h>

typedef _Float16 f16;
typedef _Float16 f16x8 __attribute__((ext_vector_type(8)));
typedef _Float16 f16x4 __attribute__((ext_vector_type(4)));
typedef float f32x4 __attribute__((ext_vector_type(4)));

#define MFMA32(a, b, c) __builtin_amdgcn_mfma_f32_16x16x32_f16((a), (b), (c), 0, 0, 0)
#define MFMA16(a, b, c) __builtin_amdgcn_mfma_f32_16x16x16f16((a), (b), (c), 0, 0, 0)

constexpr int Bs = 2, Ls = 2048, DIM = 1024, NH = 16, HD = 64;
constexpr int BL = Bs * Ls;  // 4096
constexpr float EPSV = 1e-6f;
constexpr float SCL2 = 0.125f * 1.44269504f;  // (1/sqrt(64)) * log2(e); folded into q

// async global->LDS, 16B per lane. LDS dest = wave-uniform base + lane*16.
__device__ __forceinline__ void async16(void* lds, const void* g) {
  __builtin_amdgcn_global_load_lds((const __attribute__((address_space(1))) void*)g,
                                   (__attribute__((address_space(3))) void*)lds, 16, 0, 0);
}

// BK=32 pair-XOR swizzle: rows are 64B (4 chunks); swizzle unit = row PAIR (8 chunks).
// LDS linear chunk lc <-> (pair p = lc>>3, phys ph = lc&7); global chunk g = ph ^ (p&7),
// global (row, colElems) = (2p + (g>>2), (g&3)*8). Frag read of (row r, kchunk q):
// addr elems = (r>>1)*64 + (((r&1)*4 + q) ^ ((r>>1)&7))*8.  Banks: 2-way (free).
__device__ __forceinline__ int sw32(int r, int q) {
  int p = r >> 1;
  return p * 64 + ((((r & 1) * 4 + q) ^ (p & 7)) * 8);
}

// ---------------- fp32 -> fp16 convert, all three tensors in one launch ----------------
__global__ void cvt_all_kernel(const float* __restrict__ x, const float* __restrict__ wq,
                               const float* __restrict__ wp, f16* __restrict__ xf,
                               f16* __restrict__ wqf, f16* __restrict__ wpf) {
  constexpr int NX4 = BL * DIM / 4;
  constexpr int NW4 = 3 * DIM * DIM / 4;
  int i = blockIdx.x * blockDim.x + threadIdx.x;
  const float4* src;
  f16x4* dst;
  int j;
  if (i < NX4) {
    src = (const float4*)x; dst = (f16x4*)xf; j = i;
  } else if (i < NX4 + NW4) {
    src = (const float4*)wq; dst = (f16x4*)wqf; j = i - NX4;
  } else {
    src = (const float4*)wp; dst = (f16x4*)wpf; j = i - NX4 - NW4;
  }
  float4 a = src[j];
  f16x4 o = {(f16)a.x, (f16)a.y, (f16)a.z, (f16)a.w};
  dst[j] = o;
}

// ============ QKV GEMM: 128x128 tile, BK=32, m97-style single-buffer glLDS ============
// 2 barriers/iter, 32 iters; staging = 4 glLDS insts/thread/iter; 8 b128 frag reads ->
// 16 MFMA32 per wave-iter. Swizzle via permuted per-lane GLOBAL address (glLDS-compatible).
__global__ __launch_bounds__(256) void qkv_gemm_kernel(
    const f16* __restrict__ A, const f16* __restrict__ W,
    const float* __restrict__ v0,
    const float* __restrict__ rcos, const float* __restrict__ rsin,
    const float* __restrict__ lamp,
    f16* __restrict__ qb, f16* __restrict__ kb, f16* __restrict__ vbT,
    float* __restrict__ vout) {
  constexpr int K = DIM;
  __shared__ alignas(16) f16 sA[128 * 32];
  __shared__ alignas(16) f16 sB[128 * 32];
  const int tid = threadIdx.x;
  const int w = tid >> 6, lane = tid & 63, ln = lane & 15, quad = lane >> 4;
  const int wm = w >> 1, wn = w & 1;
  const int m0 = blockIdx.y * 128, n0 = blockIdx.x * 128;

  const f16* gA[2];
  const f16* gB[2];
#pragma unroll
  for (int s = 0; s < 2; ++s) {
    int lc = tid + s * 256;
    int p = lc >> 3, g = (lc & 7) ^ (p & 7);
    int r = 2 * p + (g >> 2), ce = (g & 3) * 8;
    gA[s] = A + (size_t)(m0 + r) * K + ce;
    gB[s] = W + (size_t)(n0 + r) * K + ce;
  }

  f32x4 acc[4][4] = {};

  for (int it = 0; it < 32; ++it) {
    const int k0 = it * 32;
#pragma unroll
    for (int s = 0; s < 2; ++s) {
      async16(&sA[(tid + s * 256) * 8], gA[s] + k0);
      async16(&sB[(tid + s * 256) * 8], gB[s] + k0);
    }
    __syncthreads();  // drains glLDS vmcnt
    f16x8 a[4];
#pragma unroll
    for (int mi = 0; mi < 4; ++mi)
      a[mi] = *(const f16x8*)&sA[sw32(wm * 64 + mi * 16 + ln, quad)];
#pragma unroll
    for (int ni = 0; ni < 4; ++ni) {
      f16x8 b = *(const f16x8*)&sB[sw32(wn * 64 + ni * 16 + ln, quad)];
#pragma unroll
      for (int mi = 0; mi < 4; ++mi) acc[mi][ni] = MFMA32(a[mi], b, acc[mi][ni]);
    }
    __syncthreads();  // protect buffer before next stage
  }

  // Epilogue. Wave covers one head (64 cols). C/D: col=ln (ni tile), row=quad*4+rg (mi tile).
  const int nb = n0 + wn * 64;
  const int nsec = nb >> 10;        // 0=q, 1=k, 2=v
  const int h = (nb & 1023) >> 6;   // head

  if (nsec == 2) {
    const float lam = lamp[0];
#pragma unroll
    for (int mi = 0; mi < 4; ++mi) {
#pragma unroll
      for (int rg = 0; rg < 4; ++rg) {
        int row = m0 + wm * 64 + mi * 16 + quad * 4 + rg;
        int b = row >> 11, l = row & 2047;
        size_t base = ((size_t)(b * NH + h) * Ls + l) * HD;
        int key = l & 63;
        // PV B-frag permutation: sidx = quadk*16 + ntk*4 + j -> flash reads b128/lane
        int sidx = ((key >> 2) & 3) * 16 + (key >> 4) * 4 + (key & 3);
        size_t tb = ((size_t)(b * NH + h) * HD) * Ls + (l & ~63) + sidx;
#pragma unroll
        for (int ni = 0; ni < 4; ++ni) {
          int d = ni * 16 + ln;
          float vnew = lam * acc[mi][ni][rg] + (1.0f - lam) * v0[base + d];
          vout[base + d] = vnew;                 // fp32 output #1 (b,h,l,d)
          vbT[tb + (size_t)d * Ls] = (f16)vnew;  // (b,h,d, key-permuted l)
        }
      }
    }
  } else {
    f16* dst = nsec ? kb : qb;
    const float ratio = sqrtf(logf(2048.0f) / logf(1040.0f));
    const float post = nsec ? 1.0f : SCL2;  // fold softmax scale*log2e into q
#pragma unroll
    for (int mi = 0; mi < 4; ++mi) {
#pragma unroll
      for (int rg = 0; rg < 4; ++rg) {
        int row = m0 + wm * 64 + mi * 16 + quad * 4 + rg;
        int b = row >> 11, l = row & 2047;
        float vals[4];
#pragma unroll
        for (int ni = 0; ni < 4; ++ni) vals[ni] = acc[mi][ni][rg];
#pragma unroll
        for (int t = 0; t < 2; ++t) {
          int j = t * 16 + ln;
          float c = rcos[l * 32 + j], s = rsin[l * 32 + j];
          float x1 = vals[t], x2 = vals[t + 2];
          vals[t] = x1 * c + x2 * s;
          vals[t + 2] = -x1 * s + x2 * c;
        }
        if (nsec) {
#pragma unroll
          for (int ni = 0; ni < 4; ++ni) vals[ni] *= ratio;
        }
        float ms = vals[0] * vals[0] + vals[1] * vals[1] + vals[2] * vals[2] + vals[3] * vals[3];
        ms += __shfl_xor(ms, 1);
        ms += __shfl_xor(ms, 2);
        ms += __shfl_xor(ms, 4);
        ms += __shfl_xor(ms, 8);
        float rn = rsqrtf(ms * (1.0f / 64.0f) + EPSV) * post;
        size_t base = ((size_t)(b * NH + h) * Ls + l) * HD;
#pragma unroll
        for (int ni = 0; ni < 4; ++ni) dst[base + ni * 16 + ln] = (f16)(vals[ni] * rn);
      }
    }
  }
}

// ============ Flash attention, S^T swap + in-register P + b128 PV reads ============
// S^T = K·Q^T (A=K-frag, B=Q-frag, q pre-scaled by SCL2). S^T C-layout (key=quad*4+rg,
// q=ln) == A-operand of mfma 16x16x16 -> exp in registers feeds PV directly.
// V stored key-permuted (sidx=quadk*16+ntk*4+j): PV B-frags are conflict-free b128.
__global__ __launch_bounds__(256) void flash_kernel(
    const f16* __restrict__ qg, const f16* __restrict__ kg, const f16* __restrict__ vtg,
    f16* __restrict__ ao) {
  __shared__ alignas(16) f16 sK[2][64 * 64];
  __shared__ alignas(16) f16 sVT[2][64 * 64];  // [d][key-permuted]
  const int tid = threadIdx.x;
  const int w = tid >> 6, lane = tid & 63, ln = lane & 15, quad = lane >> 4;
  const int bx = blockIdx.x;
  const int qt = bx & 15, h = (bx >> 4) & 15, b = bx >> 8;
  const f16* Qh = qg + (size_t)(b * NH + h) * Ls * HD;
  const f16* Kh = kg + (size_t)(b * NH + h) * Ls * HD;
  const f16* VTh = vtg + (size_t)(b * NH + h) * HD * Ls;
  const int q0 = qt * 128;

  // Q as B-frags straight from global: lane n=ln (q-col), k = kk*32 + quad*8 + j
  f16x8 aq[2][2];
#pragma unroll
  for (int st = 0; st < 2; ++st)
#pragma unroll
    for (int kk = 0; kk < 2; ++kk)
      aq[st][kk] = *(const f16x8*)&Qh[(size_t)(q0 + w * 32 + st * 16 + ln) * HD + kk * 32 + quad * 8];

  f16x8 kr[2], vr[2];
  auto loadKV = [&](int k0) {
#pragma unroll
    for (int s = 0; s < 2; ++s) {
      int ch = tid + s * 256, r = ch >> 3, cg = (ch & 7) * 8;
      kr[s] = *(const f16x8*)&Kh[(size_t)(k0 + r) * HD + cg];
      vr[s] = *(const f16x8*)&VTh[(size_t)r * Ls + k0 + cg];
    }
  };
  auto stageKV = [&](int buf) {
#pragma unroll
    for (int s = 0; s < 2; ++s) {
      int ch = tid + s * 256, r = ch >> 3;
      int po = r * 64 + (((ch & 7) ^ (r & 7)) * 8);
      *(f16x8*)&sK[buf][po] = kr[s];
      *(f16x8*)&sVT[buf][po] = vr[s];
    }
  };

  f32x4 O[2][4] = {};
  float rsum[2] = {0.f, 0.f};

  loadKV(0);
  stageKV(0);
  __syncthreads();

  for (int kt = 0; kt < 32; ++kt) {
    const int cur = kt & 1;
    if (kt < 31) loadKV((kt + 1) * 64);  // global->reg prefetch across compute

    // S^T + in-register softmax -> PV A-frags (scores pre-scaled into log2 units)
    f16x4 pf[2][4];
#pragma unroll
    for (int nt = 0; nt < 4; ++nt) {
      int r = nt * 16 + ln;  // key row
      f16x8 kf0 = *(const f16x8*)&sK[cur][r * 64 + ((quad ^ (r & 7)) * 8)];
      f16x8 kf1 = *(const f16x8*)&sK[cur][r * 64 + (((4 + quad) ^ (r & 7)) * 8)];
#pragma unroll
      for (int st = 0; st < 2; ++st) {
        f32x4 z = {};
        z = MFMA32(kf0, aq[st][0], z);
        z = MFMA32(kf1, aq[st][1], z);
        float p0 = exp2f(z[0]);
        float p1 = exp2f(z[1]);
        float p2 = exp2f(z[2]);
        float p3 = exp2f(z[3]);
        rsum[st] += (p0 + p1) + (p2 + p3);
        f16x4 pk = {(f16)p0, (f16)p1, (f16)p2, (f16)p3};
        pf[st][nt] = pk;
      }
    }

    // O += P·V: per (dt, nt2) one b128 V read covers key-tiles 2nt2 and 2nt2+1
#pragma unroll
    for (int dt = 0; dt < 4; ++dt) {
      int row = dt * 16 + ln;  // d row
#pragma unroll
      for (int nt2 = 0; nt2 < 2; ++nt2) {
        f16x8 vf = *(const f16x8*)&sVT[cur][row * 64 + (((quad * 2 + nt2) ^ (row & 7)) * 8)];
        f16x4 vlo = {vf[0], vf[1], vf[2], vf[3]};
        f16x4 vhi = {vf[4], vf[5], vf[6], vf[7]};
#pragma unroll
        for (int st = 0; st < 2; ++st) {
          O[st][dt] = MFMA16(pf[st][2 * nt2], vlo, O[st][dt]);
          O[st][dt] = MFMA16(pf[st][2 * nt2 + 1], vhi, O[st][dt]);
        }
      }
    }

    if (kt < 31) stageKV(cur ^ 1);  // vmcnt wait lands here, after compute
    __syncthreads();
  }

  // epilogue: reduce row sums over quads, normalize, store fp16 attn-out (b,l,dim)
#pragma unroll
  for (int st = 0; st < 2; ++st) {
    float rs = rsum[st];
    rs += __shfl_xor(rs, 16);
    rs += __shfl_xor(rs, 32);  // lanes now hold rowsum(q-local = ln)
#pragma unroll
    for (int rg = 0; rg < 4; ++rg) {
      float inv = 1.0f / __shfl(rs, quad * 4 + rg);
      int q = q0 + w * 32 + st * 16 + quad * 4 + rg;
      size_t orow = ((size_t)b * Ls + q) * DIM + h * HD;
#pragma unroll
      for (int dt = 0; dt < 4; ++dt)
        ao[orow + dt * 16 + ln] = (f16)(O[st][dt][rg] * inv);
    }
  }
}

// ============ proj GEMM: 64x128 tile, BK=32 m97-style single-buffer glLDS ============
__global__ __launch_bounds__(256) void proj_gemm_kernel(
    const f16* __restrict__ A, const f16* __restrict__ W, float* __restrict__ out) {
  constexpr int K = DIM;
  __shared__ alignas(16) f16 sA[64 * 32];
  __shared__ alignas(16) f16 sB[128 * 32];
  const int tid = threadIdx.x;
  const int w = tid >> 6, lane = tid & 63, ln = lane & 15, quad = lane >> 4;
  const int wm = w >> 1, wn = w & 1;  // wave: 32 rows x 64 cols
  const int m0 = blockIdx.y * 64, n0 = blockIdx.x * 128;

  const f16* gA;  // 256 chunks: 1 per thread
  {
    int p = tid >> 3, g = (tid & 7) ^ (p & 7);
    gA = A + (size_t)(m0 + 2 * p + (g >> 2)) * K + (g & 3) * 8;
  }
  const f16* gB[2];
#pragma unroll
  for (int s = 0; s < 2; ++s) {
    int lc = tid + s * 256;
    int p = lc >> 3, g = (lc & 7) ^ (p & 7);
    gB[s] = W + (size_t)(n0 + 2 * p + (g >> 2)) * K + (g & 3) * 8;
  }

  f32x4 acc[2][4] = {};

  for (int it = 0; it < 32; ++it) {
    const int k0 = it * 32;
    async16(&sA[tid * 8], gA + k0);
#pragma unroll
    for (int s = 0; s < 2; ++s) async16(&sB[(tid + s * 256) * 8], gB[s] + k0);
    __syncthreads();
    f16x8 a[2];
#pragma unroll
    for (int mi = 0; mi < 2; ++mi)
      a[mi] = *(const f16x8*)&sA[sw32(wm * 32 + mi * 16 + ln, quad)];
#pragma unroll
    for (int ni = 0; ni < 4; ++ni) {
      f16x8 b = *(const f16x8*)&sB[sw32(wn * 64 + ni * 16 + ln, quad)];
#pragma unroll
      for (int mi = 0; mi < 2; ++mi) acc[mi][ni] = MFMA32(a[mi], b, acc[mi][ni]);
    }
    __syncthreads();
  }

#pragma unroll
  for (int mi = 0; mi < 2; ++mi) {
#pragma unroll
    for (int rg = 0; rg < 4; ++rg) {
      int row = m0 + wm * 32 + mi * 16 + quad * 4 + rg;
      size_t o = (size_t)row * DIM + n0 + wn * 64;
#pragma unroll
      for (int ni = 0; ni < 4; ++ni) out[o + ni * 16 + ln] = acc[mi][ni][rg];
    }
  }
}

extern "C" void kernel_launch(void* const* d_in, const int* in_sizes, int n_in,
                              void* d_out, int out_size, void* d_ws, size_t ws_size,
                              hipStream_t stream) {
  (void)in_sizes; (void)n_in; (void)out_size; (void)ws_size;
  const float* x = (const float*)d_in[0];
  const float* v0 = (const float*)d_in[1];
  const float* rcos = (const float*)d_in[2];
  const float* rsin = (const float*)d_in[3];
  const float* wqkv = (const float*)d_in[4];
  const float* wproj = (const float*)d_in[5];
  const float* lamp = (const float*)d_in[6];
  float* out = (float*)d_out;
  float* vout = out + (size_t)BL * DIM;  // output #1: blended v, (B,H,L,HD)

  char* p = (char*)d_ws;
  auto take = [&](size_t n) { char* q = p; p += ((n + 255) / 256) * 256; return q; };
  f16* xf = (f16*)take((size_t)BL * DIM * 2);
  f16* wqf = (f16*)take((size_t)3 * DIM * DIM * 2);
  f16* wpf = (f16*)take((size_t)DIM * DIM * 2);
  f16* qb = (f16*)take((size_t)BL * DIM * 2);
  f16* kb = (f16*)take((size_t)BL * DIM * 2);
  f16* vbT = (f16*)take((size_t)BL * DIM * 2);  // (b,h,d, key-permuted l)
  f16* ao = xf;  // x dead after qkv_gemm; reuse (stream-ordered)

  constexpr int NCVT4 = (BL * DIM + 3 * DIM * DIM + DIM * DIM) / 4;
  cvt_all_kernel<<<dim3(NCVT4 / 256), dim3(256), 0, stream>>>(x, wqkv, wproj, xf, wqf, wpf);

  qkv_gemm_kernel<<<dim3(3 * DIM / 128, BL / 128), dim3(256), 0, stream>>>(
      xf, wqf, v0, rcos, rsin, lamp, qb, kb, vbT, vout);

  flash_kernel<<<dim3(Bs * NH * (Ls / 128)), dim3(256), 0, stream>>>(qb, kb, vbT, ao);

  proj_gemm_kernel<<<dim3(DIM / 128, BL / 64), dim3(256), 0, stream>>>(ao, wpf, out);
}